// Round 10
// baseline (888.776 us; speedup 1.0000x reference)
//
#include <hip/hip_runtime.h>
#include <stdint.h>

#define NVOX   98280
#define S_SETS 2730
#define L_SET  36
#define D_MODEL 192
#define D_FF    384
#define N_HEADS 8
#define H_DIM   24

using s16x8 = __attribute__((ext_vector_type(8))) short;
using s16x4 = __attribute__((ext_vector_type(4))) short;
using f32x4 = __attribute__((ext_vector_type(4))) float;

__device__ __forceinline__ float bf2f(unsigned short h) {
    unsigned u = ((unsigned)h) << 16;
    return __builtin_bit_cast(float, u);
}
__device__ __forceinline__ unsigned short f2bf(float f) {
    unsigned u = __builtin_bit_cast(unsigned, f);
    u += 0x7FFF + ((u >> 16) & 1);
    return (unsigned short)(u >> 16);
}

__global__ __launch_bounds__(256)
void convert_f32_bf16(const float* __restrict__ src, short* __restrict__ dst, int n)
{
    int i = blockIdx.x * 256 + threadIdx.x;
    if (i < n) dst[i] = (short)f2bf(src[i]);
}

// ---------------------------------------------------------------------------
// Gather: qk[f]=bf16(x[v]+pos[v]); sf[f]=bf16(x[v]); v=inds[f].
// ---------------------------------------------------------------------------
__global__ __launch_bounds__(256)
void gather_kernel(const float* __restrict__ x, const float* __restrict__ pos,
                   const int* __restrict__ inds,
                   short* __restrict__ qk, short* __restrict__ sf)
{
    int f = blockIdx.x * 4 + (threadIdx.x >> 6);
    int lane = threadIdx.x & 63;
    if (lane >= 48) return;
    int v = inds[f];
    float4 a = *(const float4*)(x + (size_t)v * D_MODEL + lane * 4);
    float4 p = *(const float4*)(pos + (size_t)v * D_MODEL + lane * 4);
    s16x4 q, s;
    q[0] = (short)f2bf(a.x + p.x); q[1] = (short)f2bf(a.y + p.y);
    q[2] = (short)f2bf(a.z + p.z); q[3] = (short)f2bf(a.w + p.w);
    s[0] = (short)f2bf(a.x); s[1] = (short)f2bf(a.y);
    s[2] = (short)f2bf(a.z); s[3] = (short)f2bf(a.w);
    *(s16x4*)(qk + (size_t)f * D_MODEL + lane * 4) = q;
    *(s16x4*)(sf + (size_t)f * D_MODEL + lane * 4) = s;
}

// ---------------------------------------------------------------------------
// QKV GEMM, A-direct (round-6 winner, unchanged).
// ---------------------------------------------------------------------------
__global__ __launch_bounds__(512, 4)
void qkv_direct(const short* __restrict__ qk, const short* __restrict__ sf,
                const short* __restrict__ W, const float* __restrict__ bias,
                short* __restrict__ C, int n)
{
    __shared__ char Bs[36864];
    const int bx = blockIdx.x;                 // 0..5
    const int sec = bx >> 1, half = bx & 1;
    const int colOff = sec * 192 + half * 96;
    const short* Ap = (sec == 2) ? sf : qk;
    const short* Wp = W + (size_t)colOff * 192;
    const int rowBase = blockIdx.y * 128;
    const int tid = threadIdx.x;

    #pragma unroll
    for (int t = tid; t < 2304; t += 512) {
        int row = t / 24, c8 = t % 24;
        s16x8 v = *(const s16x8*)(Wp + (size_t)row * 192 + c8 * 8);
        *(s16x8*)(Bs + row * 384 + ((c8 * 16) ^ ((row & 7) << 4))) = v;
    }
    __syncthreads();

    const int wid = tid >> 6, lane = tid & 63;
    const int lr = lane & 15, kb = lane >> 4;
    const int arow = rowBase + wid * 16 + lr;
    const bool rv = arow < n;
    const short* Arow = Ap + (size_t)arow * 192 + kb * 8;

    f32x4 acc[6] = {};
    #pragma unroll
    for (int ks = 0; ks < 6; ++ks) {
        s16x8 a = {};
        if (rv) a = *(const s16x8*)(Arow + ks * 32);
        s16x8 b[6];
        #pragma unroll
        for (int fj = 0; fj < 6; ++fj) {
            int row = fj * 16 + lr;
            b[fj] = *(const s16x8*)(Bs + row * 384 + ((ks * 64 + kb * 16) ^ ((row & 7) << 4)));
        }
        #pragma unroll
        for (int fj = 0; fj < 6; ++fj)
            acc[fj] = __builtin_amdgcn_mfma_f32_16x16x32_bf16(a, b[fj], acc[fj], 0, 0, 0);
    }
    #pragma unroll
    for (int fj = 0; fj < 6; ++fj) {
        int col = colOff + fj * 16 + lr;
        float bv = bias[col];
        #pragma unroll
        for (int r = 0; r < 4; ++r) {
            int grow = rowBase + wid * 16 + kb * 4 + r;
            if (grow < n)
                C[(size_t)grow * 576 + col] = (short)f2bf(acc[fj][r] + bv);
        }
    }
}

// ---------------------------------------------------------------------------
// MFMA attention (round-9 verified version).
// ---------------------------------------------------------------------------
__global__ __launch_bounds__(64)
void attn_mfma(const short* __restrict__ qkv, const unsigned char* __restrict__ mask,
               short* __restrict__ attn_out)
{
    const int s = blockIdx.x >> 3;
    const int h = blockIdx.x & 7;
    __shared__ short Pl[48 * 64];
    __shared__ short Vt[32 * 64];
    char* Pb = (char*)Pl;
    char* Vb = (char*)Vt;
    const int lane = threadIdx.x;
    const int lr = lane & 15, g = lane >> 4;

    #pragma unroll
    for (int i = 0; i < 6; ++i)
        *(s16x8*)(Pl + i * 512 + lane * 8) = (s16x8){};
    #pragma unroll
    for (int i = 0; i < 4; ++i)
        *(s16x8*)(Vt + i * 512 + lane * 8) = (s16x8){};
    if (lane < L_SET) {
        const short* vrow = qkv + (size_t)(s * L_SET + lane) * 576 + 384 + h * H_DIM;
        #pragma unroll
        for (int j = 0; j < 3; ++j) {
            s16x8 v = *(const s16x8*)(vrow + j * 8);
            #pragma unroll
            for (int e = 0; e < 8; ++e) {
                int d = j * 8 + e;
                *(short*)(Vb + d * 128 + ((lane * 2) ^ ((d & 7) << 4))) = v[e];
            }
        }
    }

    s16x8 qa[3], kb[3];
    #pragma unroll
    for (int t = 0; t < 3; ++t) {
        int rr = t * 16 + lr;
        qa[t] = (s16x8){};
        kb[t] = (s16x8){};
        if (rr < L_SET && g < 3) {
            const short* base = qkv + (size_t)(s * L_SET + rr) * 576 + h * H_DIM + g * 8;
            qa[t] = *(const s16x8*)(base);
            kb[t] = *(const s16x8*)(base + 192);
        }
    }
    f32x4 sc[3][3] = {};
    #pragma unroll
    for (int mt = 0; mt < 3; ++mt)
        #pragma unroll
        for (int nt = 0; nt < 3; ++nt)
            sc[mt][nt] = __builtin_amdgcn_mfma_f32_16x16x32_bf16(qa[mt], kb[nt], sc[mt][nt], 0, 0, 0);

    const float scale = 0.20412414523193154f;
    bool colmask[3];
    #pragma unroll
    for (int nt = 0; nt < 3; ++nt) {
        int m = nt * 16 + lr;
        colmask[nt] = (m >= L_SET) || (mask[(size_t)s * L_SET + (m < L_SET ? m : 0)] != 0);
    }
    #pragma unroll
    for (int mt = 0; mt < 3; ++mt) {
        #pragma unroll
        for (int r = 0; r < 4; ++r) {
            float v[3], ev[3];
            #pragma unroll
            for (int nt = 0; nt < 3; ++nt)
                v[nt] = colmask[nt] ? -1e9f : sc[mt][nt][r] * scale;
            float mx = fmaxf(fmaxf(v[0], v[1]), v[2]);
            #pragma unroll
            for (int off = 1; off < 16; off <<= 1) mx = fmaxf(mx, __shfl_xor(mx, off, 64));
            float sm = 0.f;
            #pragma unroll
            for (int nt = 0; nt < 3; ++nt) { ev[nt] = __expf(v[nt] - mx); sm += ev[nt]; }
            #pragma unroll
            for (int off = 1; off < 16; off <<= 1) sm += __shfl_xor(sm, off, 64);
            float rinv = 1.f / sm;
            int q = mt * 16 + g * 4 + r;
            #pragma unroll
            for (int nt = 0; nt < 3; ++nt) {
                int m = nt * 16 + lr;
                *(short*)(Pb + q * 128 + ((m * 2) ^ ((q & 7) << 4))) =
                    (short)f2bf(ev[nt] * rinv);
            }
        }
    }

    f32x4 o[3][2] = {};
    #pragma unroll
    for (int ks = 0; ks < 2; ++ks) {
        s16x8 pa[3], vb[2];
        #pragma unroll
        for (int mt = 0; mt < 3; ++mt) {
            int row = mt * 16 + lr;
            pa[mt] = *(const s16x8*)(Pb + row * 128 + ((ks * 64 + g * 16) ^ ((row & 7) << 4)));
        }
        #pragma unroll
        for (int nt = 0; nt < 2; ++nt) {
            int row = nt * 16 + lr;
            vb[nt] = *(const s16x8*)(Vb + row * 128 + ((ks * 64 + g * 16) ^ ((row & 7) << 4)));
        }
        #pragma unroll
        for (int mt = 0; mt < 3; ++mt)
            #pragma unroll
            for (int nt = 0; nt < 2; ++nt)
                o[mt][nt] = __builtin_amdgcn_mfma_f32_16x16x32_bf16(pa[mt], vb[nt], o[mt][nt], 0, 0, 0);
    }

    #pragma unroll
    for (int mt = 0; mt < 3; ++mt) {
        #pragma unroll
        for (int nt = 0; nt < 2; ++nt) {
            #pragma unroll
            for (int r = 0; r < 4; ++r) {
                int q = mt * 16 + g * 4 + r;
                int d = nt * 16 + lr;
                if (q < L_SET && d < H_DIM)
                    attn_out[(size_t)(s * L_SET + q) * D_MODEL + h * H_DIM + d] =
                        (short)f2bf(o[mt][nt][r]);
            }
        }
    }
}

// ---------------------------------------------------------------------------
// Wo GEMM + LN1, wave-private: wave = 32 set-order rows x all 192 cols.
// A direct from attnb; B (Wo) direct from global (L2-resident). ZERO LDS,
// zero barriers. Epilogue: in-register LN1 (row stats via 12 adds +
// shfl_xor over the 16-lane lr group, which preserves kb bits), then
// scatter-write x1[inds[f]].
// ---------------------------------------------------------------------------
__global__ __launch_bounds__(256)
void wo_wave(const short* __restrict__ attnb, const short* __restrict__ Wo,
             const float* __restrict__ bo, const int* __restrict__ inds,
             const float* __restrict__ xin,
             const float* __restrict__ g1, const float* __restrict__ be1,
             short* __restrict__ x1, int n)
{
    const int rowBase = blockIdx.x * 128;
    const int tid = threadIdx.x;
    const int w = tid >> 6, lane = tid & 63;
    const int lr = lane & 15, kb = lane >> 4;

    f32x4 acc[2][12] = {};
    #pragma unroll
    for (int ks = 0; ks < 6; ++ks) {
        s16x8 a[2], b[12];
        #pragma unroll
        for (int fi = 0; fi < 2; ++fi) {
            int arow = rowBase + w * 32 + fi * 16 + lr;
            a[fi] = (s16x8){};
            if (arow < n)
                a[fi] = *(const s16x8*)(attnb + (size_t)arow * 192 + ks * 32 + kb * 8);
        }
        #pragma unroll
        for (int fj = 0; fj < 12; ++fj)
            b[fj] = *(const s16x8*)(Wo + (size_t)(fj * 16 + lr) * 192 + ks * 32 + kb * 8);
        #pragma unroll
        for (int fi = 0; fi < 2; ++fi)
            #pragma unroll
            for (int fj = 0; fj < 12; ++fj)
                acc[fi][fj] = __builtin_amdgcn_mfma_f32_16x16x32_bf16(a[fi], b[fj], acc[fi][fj], 0, 0, 0);
    }

    float boc[12], g1c[12], be1c[12];
    #pragma unroll
    for (int fj = 0; fj < 12; ++fj) {
        int col = fj * 16 + lr;
        boc[fj] = bo[col]; g1c[fj] = g1[col]; be1c[fj] = be1[col];
    }
    #pragma unroll
    for (int fi = 0; fi < 2; ++fi) {
        #pragma unroll
        for (int r = 0; r < 4; ++r) {
            int f = rowBase + w * 32 + fi * 16 + kb * 4 + r;
            bool valid = f < n;
            int v = valid ? inds[f] : 0;
            float t[12];
            float s = 0.f, sq = 0.f;
            #pragma unroll
            for (int fj = 0; fj < 12; ++fj) {
                int col = fj * 16 + lr;
                float xi = valid ? xin[(size_t)v * D_MODEL + col] : 0.f;
                float tv = acc[fi][fj][r] + boc[fj] + xi;
                t[fj] = tv; s += tv; sq += tv * tv;
            }
            #pragma unroll
            for (int off = 1; off < 16; off <<= 1) {
                s  += __shfl_xor(s, off, 64);
                sq += __shfl_xor(sq, off, 64);
            }
            float m = s * (1.f / 192.f);
            float iv = rsqrtf(sq * (1.f / 192.f) - m * m + 1e-5f);
            if (valid) {
                #pragma unroll
                for (int fj = 0; fj < 12; ++fj) {
                    int col = fj * 16 + lr;
                    x1[(size_t)v * D_MODEL + col] =
                        (short)f2bf((t[fj] - m) * iv * g1c[fj] + be1c[fj]);
                }
            }
        }
    }
}

// ---------------------------------------------------------------------------
// FFN, wave-private: block = 128 rows, 4 waves, wave owns 32 rows end-to-end.
// Per 96-col chunk: FF1 (A from Ax LDS, B=W1 direct global) -> Hc (bf16 LDS,
// WAVE-PRIVATE rows -> no barrier) -> FF2 (A from Hc, B=W2 direct global)
// accumulating f2 in regs. Epilogue: in-register LN2 (+x1 from Ax) ->
// +identity (xin) -> LN3 -> out. LDS 75.8 KB -> 2 blocks/CU; ONE barrier.
// ---------------------------------------------------------------------------
__global__ __launch_bounds__(256)
void ffn_wave(const short* __restrict__ x1, const short* __restrict__ W1,
              const float* __restrict__ b1, const short* __restrict__ W2,
              const float* __restrict__ b2, const float* __restrict__ xin,
              const float* __restrict__ g2, const float* __restrict__ be2,
              const float* __restrict__ gn, const float* __restrict__ bn,
              float* __restrict__ outp, int n)
{
    __shared__ char Ax[49152];         // x1 tile, swizzled (persists to LN2)
    __shared__ char Hc[26624];         // h chunk, 128 rows x 208 B, wave-private
    const int rowBase = blockIdx.x * 128;
    const int tid = threadIdx.x;
    const int w = tid >> 6, lane = tid & 63;
    const int lr = lane & 15, kb = lane >> 4;

    #pragma unroll
    for (int t = tid; t < 3072; t += 256) {
        int row = t / 24, c8 = t % 24;
        int grow = rowBase + row;
        s16x8 v = {};
        if (grow < n) v = *(const s16x8*)(x1 + (size_t)grow * 192 + c8 * 8);
        *(s16x8*)(Ax + row * 384 + ((c8 * 16) ^ ((row & 7) << 4))) = v;
    }
    __syncthreads();                   // the only barrier

    f32x4 acc2[2][12] = {};
    for (int c = 0; c < 4; ++c) {
        // FF1: 32 rows x 96 chunk cols
        f32x4 acc1[2][6] = {};
        #pragma unroll
        for (int ks = 0; ks < 6; ++ks) {
            s16x8 a[2], b[6];
            #pragma unroll
            for (int fi = 0; fi < 2; ++fi) {
                int row = w * 32 + fi * 16 + lr;
                a[fi] = *(const s16x8*)(Ax + row * 384 + ((ks * 64 + kb * 16) ^ ((row & 7) << 4)));
            }
            #pragma unroll
            for (int fj = 0; fj < 6; ++fj)
                b[fj] = *(const s16x8*)(W1 + (size_t)(c * 96 + fj * 16 + lr) * 192 + ks * 32 + kb * 8);
            #pragma unroll
            for (int fi = 0; fi < 2; ++fi)
                #pragma unroll
                for (int fj = 0; fj < 6; ++fj)
                    acc1[fi][fj] = __builtin_amdgcn_mfma_f32_16x16x32_bf16(a[fi], b[fj], acc1[fi][fj], 0, 0, 0);
        }
        // h -> Hc (wave-private rows; lgkmcnt ordering handled by compiler)
        #pragma unroll
        for (int fj = 0; fj < 6; ++fj) {
            int col = fj * 16 + lr;
            float b1v = b1[c * 96 + col];
            #pragma unroll
            for (int fi = 0; fi < 2; ++fi)
                #pragma unroll
                for (int r = 0; r < 4; ++r) {
                    int row = w * 32 + fi * 16 + kb * 4 + r;
                    *(short*)(Hc + row * 208 + col * 2) =
                        (short)f2bf(fmaxf(acc1[fi][fj][r] + b1v, 0.f));
                }
        }
        // FF2 partial: K = 96 (3 ksteps), all 192 cols
        #pragma unroll
        for (int ks = 0; ks < 3; ++ks) {
            s16x8 a[2], b[12];
            #pragma unroll
            for (int fi = 0; fi < 2; ++fi) {
                int row = w * 32 + fi * 16 + lr;
                a[fi] = *(const s16x8*)(Hc + row * 208 + ks * 64 + kb * 16);
            }
            #pragma unroll
            for (int fj = 0; fj < 12; ++fj)
                b[fj] = *(const s16x8*)(W2 + (size_t)(fj * 16 + lr) * 384 + c * 96 + ks * 32 + kb * 8);
            #pragma unroll
            for (int fi = 0; fi < 2; ++fi)
                #pragma unroll
                for (int fj = 0; fj < 12; ++fj)
                    acc2[fi][fj] = __builtin_amdgcn_mfma_f32_16x16x32_bf16(a[fi], b[fj], acc2[fi][fj], 0, 0, 0);
        }
    }

    // epilogue: LN2(x1 + f2) -> + xin -> LN3 -> out, all in registers
    float b2c[12], g2c[12], be2c[12], gnc[12], bnc[12];
    #pragma unroll
    for (int fj = 0; fj < 12; ++fj) {
        int col = fj * 16 + lr;
        b2c[fj] = b2[col]; g2c[fj] = g2[col]; be2c[fj] = be2[col];
        gnc[fj] = gn[col]; bnc[fj] = bn[col];
    }
    #pragma unroll
    for (int fi = 0; fi < 2; ++fi) {
        #pragma unroll
        for (int r = 0; r < 4; ++r) {
            int row = w * 32 + fi * 16 + kb * 4 + r;
            int gvx = rowBase + row;
            bool valid = gvx < n;
            float t[12];
            float s = 0.f, sq = 0.f;
            #pragma unroll
            for (int fj = 0; fj < 12; ++fj) {
                int col = fj * 16 + lr;
                unsigned short xv = *(const unsigned short*)(Ax + row * 384 + ((col * 2) ^ ((row & 7) << 4)));
                float tv = acc2[fi][fj][r] + b2c[fj] + bf2f(xv);
                t[fj] = tv; s += tv; sq += tv * tv;
            }
            #pragma unroll
            for (int off = 1; off < 16; off <<= 1) {
                s  += __shfl_xor(s, off, 64);
                sq += __shfl_xor(sq, off, 64);
            }
            float m1 = s * (1.f / 192.f);
            float i1 = rsqrtf(sq * (1.f / 192.f) - m1 * m1 + 1e-5f);
            float t2[12];
            float s2 = 0.f, sq2 = 0.f;
            #pragma unroll
            for (int fj = 0; fj < 12; ++fj) {
                int col = fj * 16 + lr;
                float xi = valid ? xin[(size_t)gvx * D_MODEL + col] : 0.f;
                float v2 = (t[fj] - m1) * i1 * g2c[fj] + be2c[fj] + xi;
                t2[fj] = v2; s2 += v2; sq2 += v2 * v2;
            }
            #pragma unroll
            for (int off = 1; off < 16; off <<= 1) {
                s2  += __shfl_xor(s2, off, 64);
                sq2 += __shfl_xor(sq2, off, 64);
            }
            float m2 = s2 * (1.f / 192.f);
            float i2 = rsqrtf(sq2 * (1.f / 192.f) - m2 * m2 + 1e-5f);
            if (valid) {
                #pragma unroll
                for (int fj = 0; fj < 12; ++fj) {
                    int col = fj * 16 + lr;
                    outp[(size_t)gvx * D_MODEL + col] = (t2[fj] - m2) * i2 * gnc[fj] + bnc[fj];
                }
            }
        }
    }
}

// ---------------------------------------------------------------------------
extern "C" void kernel_launch(void* const* d_in, const int* in_sizes, int n_in,
                              void* d_out, int out_size, void* d_ws, size_t ws_size,
                              hipStream_t stream)
{
    (void)in_sizes; (void)n_in; (void)out_size;
    const int N = NVOX;
    const float* src = (const float*)d_in[0];
    const int* inds[2] = {(const int*)d_in[1], (const int*)d_in[2]};
    const unsigned char* mask[2] = {(const unsigned char*)d_in[3], (const unsigned char*)d_in[4]};
    const float* pos[2] = {(const float*)d_in[5], (const float*)d_in[6]};
    const float* Wqkv = (const float*)d_in[7];
    const float* bqkv = (const float*)d_in[8];
    const float* Wo   = (const float*)d_in[9];
    const float* bo   = (const float*)d_in[10];
    const float* W1   = (const float*)d_in[11];
    const float* b1   = (const float*)d_in[12];
    const float* W2   = (const float*)d_in[13];
    const float* b2   = (const float*)d_in[14];
    const float* g1   = (const float*)d_in[15];
    const float* be1  = (const float*)d_in[16];
    const float* g2   = (const float*)d_in[17];
    const float* be2  = (const float*)d_in[18];
    const float* gn   = (const float*)d_in[19];
    const float* bn   = (const float*)d_in[20];

    float* out = (float*)d_out;
    short* wsS = (short*)d_ws;

    const size_t NE = (size_t)N * D_MODEL;
    short* wqkv_b = wsS;
    short* wo_b   = wsS + 221184;
    short* w1_b   = wsS + 294912;
    short* w2_b   = wsS + 442368;
    const size_t base = 1048576;
    short* qk    = wsS + base;
    short* sf    = qk + NE;
    short* qkvb  = sf + NE;
    short* attnb = qkvb + 3 * NE;
    short* x1    = attnb + NE;

    if (ws_size < (base + 7 * NE) * sizeof(short)) return;

    const dim3 blk(256);
    convert_f32_bf16<<<dim3(864), blk, 0, stream>>>(Wqkv, wqkv_b, 221184);
    convert_f32_bf16<<<dim3(288), blk, 0, stream>>>(Wo,   wo_b,   73728);
    convert_f32_bf16<<<dim3(576), blk, 0, stream>>>(W1,   w1_b,   147456);
    convert_f32_bf16<<<dim3(576), blk, 0, stream>>>(W2,   w2_b,   147456);

    const int RT = (N + 127) / 128;                  // 768 row tiles
    for (int i = 0; i < 2; ++i) {
        const float* xin = (i == 0) ? src : out;
        gather_kernel<<<dim3(24570), blk, 0, stream>>>(xin, pos[i], inds[i], qk, sf);
        qkv_direct<<<dim3(6, RT), dim3(512), 0, stream>>>(
            qk, sf, wqkv_b + (size_t)i * 110592, bqkv + i * 576, qkvb, N);
        attn_mfma<<<dim3(S_SETS * N_HEADS), dim3(64), 0, stream>>>(qkvb, mask[i], attnb);
        wo_wave<<<dim3(RT), blk, 0, stream>>>(
            attnb, wo_b + (size_t)i * 36864, bo + i * 192, inds[i], xin,
            g1 + i * 192, be1 + i * 192, x1, N);
        ffn_wave<<<dim3(RT), blk, 0, stream>>>(
            x1, w1_b + (size_t)i * 73728, b1 + i * 384, w2_b + (size_t)i * 73728,
            b2 + i * 192, xin, g2 + i * 192, be2 + i * 192,
            gn + i * 192, bn + i * 192, out, N);
    }
}